// Round 1
// baseline (464.379 us; speedup 1.0000x reference)
//
#include <hip/hip_runtime.h>
#include <stdint.h>

// Problem constants
#define T_DIM 2048
#define B_DIM 4
#define D_DIM 1024
#define H_NUM 16
#define HD 64
#define MROWS (T_DIM * B_DIM)     // 8192 flattened (t*B+b) rows
#define QKV_N (3 * D_DIM)         // 3072
#define ATT_SCALE 0.125f          // 1/sqrt(64)

typedef unsigned short u16;
typedef __bf16 bf16x8 __attribute__((ext_vector_type(8)));
typedef float f32x4 __attribute__((ext_vector_type(4)));
typedef u16 u16x4 __attribute__((ext_vector_type(4)));
typedef u16 u16x8 __attribute__((ext_vector_type(8)));

__device__ __forceinline__ u16 f2bf(float f) {
  union { float f; unsigned u; } v; v.f = f;
  unsigned r = v.u + 0x7fffu + ((v.u >> 16) & 1u);
  return (u16)(r >> 16);
}

// async global->LDS, 16B per lane. LDS dest is readfirstlane'd base + lane*16.
__device__ __forceinline__ void async_copy16(void* lds, const void* g) {
  __builtin_amdgcn_global_load_lds((__attribute__((address_space(1))) void*)(g),
                                   (__attribute__((address_space(3))) void*)(lds),
                                   16, 0, 0);
}

// ---------------- fp32 -> bf16 cast (memory-bound) ----------------
__global__ __launch_bounds__(256) void cast_f32_bf16(
    const float* __restrict__ src, u16* __restrict__ dst, int n4) {
  int i = blockIdx.x * 256 + threadIdx.x;
  if (i >= n4) return;
  float4 v = reinterpret_cast<const float4*>(src)[i];
  u16x4 o = {f2bf(v.x), f2bf(v.y), f2bf(v.z), f2bf(v.w)};
  reinterpret_cast<u16x4*>(dst)[i] = o;
}

// ---------------- bf16 GEMM: C[M][N] = A[M][K] * B[N][K]^T ----------------
// m97 structure: 128x128 tile, BK=64, 256 threads = 4 waves (2x2), each wave
// 64x64 via 4x4 of 16x16x32 MFMA. Single-buffered LDS, global_load_lds x16B.
template <int OUT_F32_BIAS>
__global__ __launch_bounds__(256) void gemm_bt(
    const u16* __restrict__ A, const u16* __restrict__ Bm,
    u16* __restrict__ Cb, float* __restrict__ Cf, const float* __restrict__ bias,
    int M, int N, int K) {
  __shared__ __attribute__((aligned(16))) u16 As[128 * 64];
  __shared__ __attribute__((aligned(16))) u16 Bs[128 * 64];

  const int tid = threadIdx.x;
  const int lane = tid & 63, wid = tid >> 6;
  const int l15 = lane & 15, lg = lane >> 4;
  const int wr = wid >> 1, wc = wid & 1;
  const int m0 = blockIdx.y * 128, n0 = blockIdx.x * 128;

  f32x4 acc[4][4];
#pragma unroll
  for (int i = 0; i < 4; i++)
#pragma unroll
    for (int j = 0; j < 4; j++) acc[i][j] = (f32x4){0.f, 0.f, 0.f, 0.f};

  const int srow = tid >> 3;        // 0..31
  const int scol = (tid & 7) * 8;   // element col within BK
  const u16* gA = A + (size_t)(m0 + srow) * K + scol;
  const u16* gB = Bm + (size_t)(n0 + srow) * K + scol;
  u16* lA = As + tid * 8;
  u16* lB = Bs + tid * 8;

  const int KT = K >> 6;
  for (int kt = 0; kt < KT; ++kt) {
    const int kofs = kt * 64;
#pragma unroll
    for (int p = 0; p < 4; ++p) {
      async_copy16(lA + p * 256 * 8, gA + (size_t)(p * 32) * K + kofs);
      async_copy16(lB + p * 256 * 8, gB + (size_t)(p * 32) * K + kofs);
    }
    __syncthreads();  // drains vmcnt (gload_lds) + lgkm
#pragma unroll
    for (int kk = 0; kk < 2; ++kk) {
      bf16x8 af[4], bfr[4];
#pragma unroll
      for (int mt = 0; mt < 4; ++mt)
        af[mt] = *reinterpret_cast<const bf16x8*>(
            &As[(wr * 64 + mt * 16 + l15) * 64 + kk * 32 + lg * 8]);
#pragma unroll
      for (int nt = 0; nt < 4; ++nt)
        bfr[nt] = *reinterpret_cast<const bf16x8*>(
            &Bs[(wc * 64 + nt * 16 + l15) * 64 + kk * 32 + lg * 8]);
#pragma unroll
      for (int mt = 0; mt < 4; ++mt)
#pragma unroll
        for (int nt = 0; nt < 4; ++nt)
          acc[mt][nt] = __builtin_amdgcn_mfma_f32_16x16x32_bf16(
              af[mt], bfr[nt], acc[mt][nt], 0, 0, 0);
    }
    __syncthreads();
  }

  // epilogue: C/D layout col=lane&15, row=(lane>>4)*4+reg
#pragma unroll
  for (int mt = 0; mt < 4; ++mt) {
#pragma unroll
    for (int r = 0; r < 4; ++r) {
      const int row = m0 + wr * 64 + mt * 16 + lg * 4 + r;
#pragma unroll
      for (int nt = 0; nt < 4; ++nt) {
        const int col = n0 + wc * 64 + nt * 16 + l15;
        float v = acc[mt][nt][r];
        if (OUT_F32_BIAS) {
          Cf[(size_t)row * N + col] = v + bias[col];
        } else {
          Cb[(size_t)row * N + col] = f2bf(v);
        }
      }
    }
  }
}

// ---------------- causal flash attention ----------------
// Grid: (T/64, B*H). Block 256 = 4 waves; wave w owns Q rows q0+16w..+15.
// qkv row m = t*B+b, cols: Q at h*64, K at 1024+h*64, V at 2048+h*64.
__global__ __launch_bounds__(256) void attn_kernel(
    const u16* __restrict__ qkv, u16* __restrict__ aout) {
  __shared__ __attribute__((aligned(16))) u16 Ks[64 * 64];
  __shared__ __attribute__((aligned(16))) u16 Vf[2 * 4 * 64 * 8];  // V B-frags
  __shared__ __attribute__((aligned(16))) u16 Ps[4][16 * 64];      // per-wave P

  const int tid = threadIdx.x;
  const int lane = tid & 63, w = tid >> 6;
  const int l15 = lane & 15, lg = lane >> 4;
  const int qt = blockIdx.x;
  const int bh = blockIdx.y;
  const int b = bh >> 4, h = bh & 15;
  const int q0 = qt * 64;
  const int qbase = q0 + w * 16;

  // Q fragments held in registers for the whole kernel
  bf16x8 aq[2];
  {
    const int trow = qbase + l15;
    const u16* qp = qkv + ((size_t)trow * B_DIM + b) * QKV_N + h * HD + lg * 8;
    aq[0] = *reinterpret_cast<const bf16x8*>(qp);
    aq[1] = *reinterpret_cast<const bf16x8*>(qp + 32);
  }

  f32x4 acc_o[4];
#pragma unroll
  for (int i = 0; i < 4; i++) acc_o[i] = (f32x4){0.f, 0.f, 0.f, 0.f};
  float mrow[4] = {-1e30f, -1e30f, -1e30f, -1e30f};
  float lrow[4] = {0.f, 0.f, 0.f, 0.f};

  const int srow = tid >> 3;
  const int scol = (tid & 7) * 8;
  u16* lK = Ks + tid * 8;

  const int ntiles = qt + 1;  // causal: kv tiles 0..qt
  for (int kt = 0; kt < ntiles; ++kt) {
    const int kv0 = kt * 64;
    // stage K tile (64x64 bf16, row-major) via async copy
#pragma unroll
    for (int p = 0; p < 2; ++p) {
      const u16* gK = qkv + ((size_t)(kv0 + p * 32 + srow) * B_DIM + b) * QKV_N +
                      D_DIM + h * HD + scol;
      async_copy16(lK + p * 256 * 8, gK);
    }
    // V: global -> regs -> scatter into MFMA B-fragment layout
    u16x8 vv[2];
#pragma unroll
    for (int p = 0; p < 2; ++p) {
      const u16* gV = qkv + ((size_t)(kv0 + p * 32 + srow) * B_DIM + b) * QKV_N +
                      2 * D_DIM + h * HD + scol;
      vv[p] = *reinterpret_cast<const u16x8*>(gV);
    }
#pragma unroll
    for (int p = 0; p < 2; ++p) {
      const int jj = srow & 7;        // kv % 8
      const int lgrp = srow >> 3;     // (kv%32)/8
#pragma unroll
      for (int j = 0; j < 8; ++j) {
        const int d = scol + j;
        Vf[(((p * 4) + (d >> 4)) * 64 + lgrp * 16 + (d & 15)) * 8 + jj] = vv[p][j];
      }
    }
    __syncthreads();

    // S = Q K^T  (per wave: 16 x 64)
    f32x4 accs[4];
#pragma unroll
    for (int jt = 0; jt < 4; jt++) accs[jt] = (f32x4){0.f, 0.f, 0.f, 0.f};
#pragma unroll
    for (int kk = 0; kk < 2; ++kk) {
#pragma unroll
      for (int jt = 0; jt < 4; ++jt) {
        bf16x8 bk = *reinterpret_cast<const bf16x8*>(
            &Ks[(jt * 16 + l15) * 64 + kk * 32 + lg * 8]);
        accs[jt] = __builtin_amdgcn_mfma_f32_16x16x32_bf16(aq[kk], bk, accs[jt], 0, 0, 0);
      }
    }
    // scale + causal mask (only the diagonal tile needs masking)
    const bool diag = (kt == qt);
#pragma unroll
    for (int jt = 0; jt < 4; ++jt)
#pragma unroll
      for (int r = 0; r < 4; ++r) {
        float s = accs[jt][r] * ATT_SCALE;
        if (diag) {
          const int col = kv0 + jt * 16 + l15;
          const int row = qbase + lg * 4 + r;
          if (col > row) s = -1e30f;
        }
        accs[jt][r] = s;
      }
    // online softmax, rows live in reg r across 16-lane groups
#pragma unroll
    for (int r = 0; r < 4; ++r) {
      float mx = fmaxf(fmaxf(accs[0][r], accs[1][r]), fmaxf(accs[2][r], accs[3][r]));
#pragma unroll
      for (int off = 1; off < 16; off <<= 1) mx = fmaxf(mx, __shfl_xor(mx, off, 64));
      const float mnew = fmaxf(mrow[r], mx);
      const float corr = __expf(mrow[r] - mnew);
      mrow[r] = mnew;
      float rs = 0.f;
#pragma unroll
      for (int jt = 0; jt < 4; ++jt) {
        float p = __expf(accs[jt][r] - mnew);
        accs[jt][r] = p;
        rs += p;
      }
#pragma unroll
      for (int off = 1; off < 16; off <<= 1) rs += __shfl_xor(rs, off, 64);
      lrow[r] = lrow[r] * corr + rs;
#pragma unroll
      for (int dj = 0; dj < 4; ++dj) acc_o[dj][r] *= corr;
    }
    // P -> LDS (per-wave buffer, no cross-wave barrier needed)
#pragma unroll
    for (int jt = 0; jt < 4; ++jt)
#pragma unroll
      for (int r = 0; r < 4; ++r)
        Ps[w][(lg * 4 + r) * 64 + jt * 16 + l15] = f2bf(accs[jt][r]);
    // O += P V
#pragma unroll
    for (int ks = 0; ks < 2; ++ks) {
      bf16x8 ap = *reinterpret_cast<const bf16x8*>(&Ps[w][l15 * 64 + ks * 32 + lg * 8]);
#pragma unroll
      for (int dj = 0; dj < 4; ++dj) {
        bf16x8 bv = *reinterpret_cast<const bf16x8*>(&Vf[((ks * 4 + dj) * 64 + lane) * 8]);
        acc_o[dj] = __builtin_amdgcn_mfma_f32_16x16x32_bf16(ap, bv, acc_o[dj], 0, 0, 0);
      }
    }
    __syncthreads();
  }

  // epilogue: O /= lsum, write bf16 to aout[m][h*64+d]
#pragma unroll
  for (int r = 0; r < 4; ++r) {
    const float inv = 1.0f / lrow[r];
    const int trow = qbase + lg * 4 + r;
    u16* op = aout + ((size_t)trow * B_DIM + b) * D_DIM + h * HD;
#pragma unroll
    for (int dj = 0; dj < 4; ++dj) op[dj * 16 + l15] = f2bf(acc_o[dj][r] * inv);
  }
}

// ---------------- launch ----------------
extern "C" void kernel_launch(void* const* d_in, const int* in_sizes, int n_in,
                              void* d_out, int out_size, void* d_ws, size_t ws_size,
                              hipStream_t stream) {
  (void)in_sizes; (void)n_in; (void)out_size; (void)ws_size;
  const float* x = (const float*)d_in[0];
  const float* Wqkv = (const float*)d_in[1];
  const float* Wout = (const float*)d_in[2];
  const float* bout = (const float*)d_in[3];
  float* out = (float*)d_out;

  // workspace layout (bf16 u16 units), total ~92.3 MB
  u16* xb = (u16*)d_ws;                               // [8192][1024]
  u16* wqkvb = xb + (size_t)MROWS * D_DIM;            // [3072][1024]
  u16* woutb = wqkvb + (size_t)QKV_N * D_DIM;         // [1024][1024]
  u16* qkv = woutb + (size_t)D_DIM * D_DIM;           // [8192][3072]
  u16* aout = qkv + (size_t)MROWS * QKV_N;            // [8192][1024]

  {
    int n4 = MROWS * D_DIM / 4;
    cast_f32_bf16<<<(n4 + 255) / 256, 256, 0, stream>>>(x, xb, n4);
  }
  {
    int n4 = QKV_N * D_DIM / 4;
    cast_f32_bf16<<<(n4 + 255) / 256, 256, 0, stream>>>(Wqkv, wqkvb, n4);
  }
  {
    int n4 = D_DIM * D_DIM / 4;
    cast_f32_bf16<<<(n4 + 255) / 256, 256, 0, stream>>>(Wout, woutb, n4);
  }

  // qkv = x @ W_qkv^T   (8192 x 3072, K=1024)
  gemm_bt<0><<<dim3(QKV_N / 128, MROWS / 128), 256, 0, stream>>>(
      xb, wqkvb, qkv, nullptr, nullptr, MROWS, QKV_N, D_DIM);

  // causal attention
  attn_kernel<<<dim3(T_DIM / 64, B_DIM * H_NUM), 256, 0, stream>>>(qkv, aout);

  // out = attn_out @ W_out^T + b_out  (fp32)
  gemm_bt<1><<<dim3(D_DIM / 128, MROWS / 128), 256, 0, stream>>>(
      aout, woutb, nullptr, out, bout, MROWS, D_DIM, D_DIM);
}